// Round 7
// baseline (444.571 us; speedup 1.0000x reference)
//
#include <hip/hip_runtime.h>

#define H 1024
#define W 1024
#define HW (H * W)
#define TROWS 16              // output rows per block
#define LROWS 20              // staged input rows = TROWS + 4 halo
#define SLOTF 1024            // floats per LDS row slot

typedef __attribute__((address_space(3))) float lds_f;
typedef const __attribute__((address_space(1))) float g_f;

// Direct global->LDS DMA, 16B per lane. Dest = wave-uniform base + lane*16
// (our layout: wave w owns floats [256w, 256w+256) of the slot). Src per-lane.
__device__ __forceinline__ void gload16(const float* g, float* l) {
    __builtin_amdgcn_global_load_lds((g_f*)g, (lds_f*)l, 16, 0, 0);
}

// Counted wait + raw barrier in ONE asm with memory clobber: no memory op
// (ds_read, global store, DMA issue) can be moved across it by the compiler,
// which is what makes the FIFO vmcnt accounting below sound.
template<int N>
__device__ __forceinline__ void wait_vm_barrier() {
    asm volatile("s_waitcnt vmcnt(%0)\n\ts_barrier" :: "i"(N) : "memory");
}

// Issue one row-DMA into a slot (row clamped for edge replication).
__device__ __forceinline__ void stage(const float* px, int row, float* slotbase, int wq, int t) {
    row = row < 0 ? 0 : (row > H - 1 ? H - 1 : row);
    gload16(px + (size_t)row * W + (t << 2), slotbase + wq);
}

// Bit-exact emulation of the numpy fp32 reference (verified R6, absmax 0):
// direct 9-tap correlation, row-major tap order, sequential fp32 adds.
// fmaf by +-2/+-4 is bit-identical to mul+add (power-of-2 products exact).
// det = p1 - p2 must NOT be contracted -> contract(off).
__device__ __forceinline__ float score_ref(
    float a00, float a01, float a02,
    float a10, float a11, float a12,
    float a20, float a21, float a22)
{
#pragma clang fp contract(off)
    float gxx = fmaf(-2.0f, a01, a00);
    gxx = gxx + a02;
    gxx = fmaf(2.0f, a10, gxx);
    gxx = fmaf(-4.0f, a11, gxx);
    gxx = fmaf(2.0f, a12, gxx);
    gxx = gxx + a20;
    gxx = fmaf(-2.0f, a21, gxx);
    gxx = gxx + a22;
    float gxy = a02 - a00;
    gxy = gxy + a20;
    gxy = gxy - a22;
    float gyy = fmaf(2.0f, a01, a00);
    gyy = gyy + a02;
    gyy = fmaf(-2.0f, a10, gyy);
    gyy = fmaf(-4.0f, a11, gyy);
    gyy = fmaf(-2.0f, a12, gyy);
    gyy = gyy + a20;
    gyy = fmaf(2.0f, a21, gyy);
    gyy = gyy + a22;

    float p1 = gxx * gyy;
    float p2 = gxy * gxy;
    float det = p1 - p2;
    float s = fabsf(det);
    return s > 1e-6f ? s : 1e-6f;
}

struct Row8 { float a[8]; };   // input cols c-2 .. c+5 (c = 4*t)

// Window from an LDS slot with horizontal edge clamp (only lanes 0 / 255).
// b64 @ c-2 (8B aligned), b128 @ c (16B aligned), b64 @ c+4 (8B aligned).
__device__ __forceinline__ Row8 read_win(const float* p, int t)
{
    const int c = t << 2;
    const float2 L  = *(const float2*)(p + (t == 0 ? 0 : c - 2));
    const float4 M  = *(const float4*)(p + c);
    const float2 Rr = *(const float2*)(p + (t == 255 ? 1022 : c + 4));
    Row8 r;
    r.a[0] = L.x;
    r.a[1] = (t == 0) ? L.x : L.y;        // col -1 -> x[0]
    r.a[2] = M.x; r.a[3] = M.y; r.a[4] = M.z; r.a[5] = M.w;
    r.a[6] = (t == 255) ? Rr.y : Rr.x;    // col 1024 -> x[1023]
    r.a[7] = Rr.y;                         // col 1025 -> x[1023] (Rr.y = p[1023])
    return r;
}

struct S6 { float s[6]; };   // scores at cols c-1 .. c+4

__device__ __forceinline__ S6 score_row_exact(const Row8& A, const Row8& B, const Row8& C)
{
    S6 o;
#pragma unroll
    for (int i = 0; i < 6; ++i)
        o.s[i] = score_ref(A.a[i], A.a[i + 1], A.a[i + 2],
                           B.a[i], B.a[i + 1], B.a[i + 2],
                           C.a[i], C.a[i + 1], C.a[i + 2]);
    return o;
}

// ---------------- K1: scores + NMS mask -> out (UNNORMALIZED), plane max ----
// 2D tile, all 20 row-DMAs issued up front (max MLP, no serial row chain).
// vmcnt accounting: issue order = 20 DMAs, then stores interleaved with rows.
// Row r needs DMA idx r+4; at its wait, ops issued = 20 + r, ops that must
// be retired = r+5 oldest (all DMAs) -> wait vmcnt((20+r)-(r+5)) = 15, const.
// Stores are always the newest ops so they never gate the wait.
__global__ __launch_bounds__(256) void hess_score_nms(
    const float* __restrict__ x, float* __restrict__ out,
    unsigned int* __restrict__ pmax)
{
    __shared__ float lds[LROWS * SLOTF];   // 80 KiB -> 2 blocks/CU
    const int plane = blockIdx.y;
    const int y0 = blockIdx.x * TROWS;
    const int t = threadIdx.x;
    const int wq = (t >> 6) << 8;
    const float* px = x + (size_t)plane * HW;
    float* po = out + (size_t)plane * HW;

    // Issue ALL tile DMAs back-to-back: input rows y0-2 .. y0+17 -> slots 0..19.
#pragma unroll
    for (int k = 0; k < LROWS; ++k)
        stage(px, y0 - 2 + k, lds + k * SLOTF, wq, t);

    // Prologue needs slots 0..3 (DMA 0..3): newer = 16 DMAs outstanding ok.
    wait_vm_barrier<16>();
    Row8 rm2 = read_win(lds, t);               // input row y0-2
    Row8 r0  = read_win(lds + SLOTF, t);       // input row y0-1
    Row8 r1  = read_win(lds + 2 * SLOTF, t);   // input row y0
    Row8 r2  = read_win(lds + 3 * SLOTF, t);   // input row y0+1

    S6 zero;
#pragma unroll
    for (int i = 0; i < 6; ++i) zero.s[i] = 0.0f;

    S6 sp = zero;                              // score row y0-1 (OOB -> zeros)
    if (y0 > 0) sp = score_row_exact(rm2, r0, r1);
    S6 sc_ = score_row_exact(r0, r1, r2);      // score row y0

    float smax = 1e-6f;
    for (int r = 0; r < TROWS; ++r) {
        const int sy = y0 + r;
        wait_vm_barrier<15>();                 // DMA r+4 retired (see header)

        Row8 r3 = read_win(lds + (r + 4) * SLOTF, t);   // input row sy+2

        S6 sn = zero;                          // score row sy+1 (OOB -> zeros)
        if (sy + 1 < H) sn = score_row_exact(r1, r2, r3);

        // Shared-column NMS max: bit-identical to the 9-way tree (max is
        // exactly associative/commutative); fuses to v_max3_f32.
        float m3[6];
#pragma unroll
        for (int k = 0; k < 6; ++k)
            m3[k] = fmaxf(fmaxf(sp.s[k], sc_.s[k]), sn.s[k]);

        float4 o;
        float* ov = (float*)&o;
#pragma unroll
        for (int j = 0; j < 4; ++j) {
            float s = sc_.s[j + 1];
            smax = fmaxf(smax, s);
            float m = fmaxf(fmaxf(m3[j], m3[j + 1]), m3[j + 2]);
            ov[j] = (s == m) ? s : 0.0f;
        }
        *(float4*)(po + (size_t)sy * W + (t << 2)) = o;

        r1 = r2; r2 = r3;
        sp = sc_; sc_ = sn;
    }

#pragma unroll
    for (int off = 32; off > 0; off >>= 1)
        smax = fmaxf(smax, __shfl_down(smax, off));
    if ((t & 63) == 0)
        atomicMax(pmax + plane, __float_as_uint(smax));
}

// ---------------- K2: in-place normalize (pure streaming) -------------------
__global__ __launch_bounds__(256) void hess_scale(
    float* __restrict__ out, const unsigned int* __restrict__ pmax)
{
    const int plane = blockIdx.y;
    const float inv = 1.0f / __uint_as_float(pmax[plane]);
    float4* p = (float4*)(out + (size_t)plane * HW);
    const int idx = blockIdx.x * 256 + threadIdx.x;   // 0 .. 65535
#pragma unroll
    for (int k = 0; k < 4; ++k) {
        float4 v = p[idx + (k << 16)];
        v.x *= inv; v.y *= inv; v.z *= inv; v.w *= inv;
        p[idx + (k << 16)] = v;
    }
}

extern "C" void kernel_launch(void* const* d_in, const int* in_sizes, int n_in,
                              void* d_out, int out_size, void* d_ws, size_t ws_size,
                              hipStream_t stream) {
    const float* x = (const float*)d_in[0];
    float* out = (float*)d_out;
    unsigned int* pmax = (unsigned int*)d_ws;
    const int planes = in_sizes[0] / HW;   // 48

    hipMemsetAsync(pmax, 0, planes * sizeof(unsigned int), stream);

    dim3 grid1(H / TROWS, planes);         // 64 x 48 = 3072 blocks
    hess_score_nms<<<grid1, 256, 0, stream>>>(x, out, pmax);

    dim3 grid2(256, planes);               // 256 thr x 4 float4 = 4096 f/blk
    hess_scale<<<grid2, 256, 0, stream>>>(out, pmax);
}

// Round 8
// 414.259 us; speedup vs baseline: 1.0732x; 1.0732x over previous
//
#include <hip/hip_runtime.h>

#define H 1024
#define W 1024
#define HW (H * W)
#define STRIP 32

// Bit-exact emulation of the numpy fp32 reference (verified R6/R7, absmax 0):
// direct 9-tap correlation, row-major tap order, sequential fp32 adds.
// fmaf by +-2/+-4 is bit-identical to mul+add (power-of-2 products exact).
// det = p1 - p2 must NOT be contracted -> contract(off).
__device__ __forceinline__ float score_ref(
    float a00, float a01, float a02,
    float a10, float a11, float a12,
    float a20, float a21, float a22)
{
#pragma clang fp contract(off)
    float gxx = fmaf(-2.0f, a01, a00);
    gxx = gxx + a02;
    gxx = fmaf(2.0f, a10, gxx);
    gxx = fmaf(-4.0f, a11, gxx);
    gxx = fmaf(2.0f, a12, gxx);
    gxx = gxx + a20;
    gxx = fmaf(-2.0f, a21, gxx);
    gxx = gxx + a22;
    float gxy = a02 - a00;
    gxy = gxy + a20;
    gxy = gxy - a22;
    float gyy = fmaf(2.0f, a01, a00);
    gyy = gyy + a02;
    gyy = fmaf(-2.0f, a10, gyy);
    gyy = fmaf(-4.0f, a11, gyy);
    gyy = fmaf(-2.0f, a12, gyy);
    gyy = gyy + a20;
    gyy = fmaf(2.0f, a21, gyy);
    gyy = gyy + a22;

    float p1 = gxx * gyy;
    float p2 = gxy * gxy;
    float det = p1 - p2;
    float s = fabsf(det);
    return s > 1e-6f ? s : 1e-6f;
}

struct Row8 { float a[8]; };   // input cols c-2 .. c+5 (c = 4*t)

// One row window per thread, aligned loads only (f4 @c, f2 @c-2, f2 @c+4);
// horizontal edge-replicate fixups only affect threads 0 and 255.
// These are plain global_load_dwordx4/x2 — the instruction class m13 proves
// sustains 6.3 TB/s (unlike the global_load_lds DMA path, measured ~2 TB/s).
__device__ __forceinline__ Row8 load_row8(const float* __restrict__ px, int row, int t)
{
    row = row < 0 ? 0 : (row > H - 1 ? H - 1 : row);
    const float* prow = px + (size_t)row * W;
    const int c = t << 2;
    const float4 M  = *(const float4*)(prow + c);
    const float2 L  = *(const float2*)(prow + (t == 0 ? 0 : c - 2));
    const float2 Rr = *(const float2*)(prow + (t == 255 ? 1022 : c + 4));
    Row8 r;
    r.a[0] = L.x;
    r.a[1] = (t == 0) ? L.x : L.y;        // col -1 -> x[0]
    r.a[2] = M.x; r.a[3] = M.y; r.a[4] = M.z; r.a[5] = M.w;
    r.a[6] = (t == 255) ? Rr.y : Rr.x;    // col 1024 -> x[1023]
    r.a[7] = Rr.y;                         // col 1025 -> x[1023]
    return r;
}

struct S6 { float s[6]; };   // scores at cols c-1 .. c+4

__device__ __forceinline__ S6 score_row_exact(const Row8& A, const Row8& B, const Row8& C)
{
    S6 o;
#pragma unroll
    for (int i = 0; i < 6; ++i)
        o.s[i] = score_ref(A.a[i], A.a[i + 1], A.a[i + 2],
                           B.a[i], B.a[i + 1], B.a[i + 2],
                           C.a[i], C.a[i + 1], C.a[i + 2]);
    return o;
}

// ---------------- K1: scores + NMS mask -> out (UNNORMALIZED), plane max ----
// Register ring of 8 Row8s (64 VGPRs), prefetch distance 4 rows (~12 loads
// in flight/thread). No LDS, no barriers, no manual waitcnt: the compiler
// emits precise per-register vmcnt waits. __launch_bounds__(256,4) grants a
// 128-VGPR budget so the ring is NOT rematerialized (R0's VGPR=32 failure).
__global__ __launch_bounds__(256, 4) void hess_score_nms(
    const float* __restrict__ x, float* __restrict__ out,
    unsigned int* __restrict__ pmax)
{
    const int plane = blockIdx.y;
    const int y0 = blockIdx.x * STRIP;
    const int t = threadIdx.x;
    const float* px = x + (size_t)plane * HW;
    float* po = out + (size_t)plane * HW;

    // ring[(m+2)&7] holds input row y0+m. Prologue: rows y0-2 .. y0+5.
    Row8 ring[8];
#pragma unroll
    for (int k = 0; k < 8; ++k)
        ring[k] = load_row8(px, y0 - 2 + k, t);

    Row8 r1 = ring[2];                     // input row y0
    Row8 r2 = ring[3];                     // input row y0+1

    S6 zero;
#pragma unroll
    for (int i = 0; i < 6; ++i) zero.s[i] = 0.0f;

    S6 sp = zero;                          // score row y0-1 (OOB -> zeros)
    if (y0 > 0) sp = score_row_exact(ring[0], ring[1], r1);
    S6 sc_ = score_row_exact(ring[1], r1, r2);   // score row y0

    float smax = 1e-6f;
    for (int io = 0; io < STRIP; io += 8) {
#pragma unroll
        for (int k = 0; k < 8; ++k) {
            const int i = io + k;
            const int sy = y0 + i;
            // consume input row sy+2 (slot (i+4)&7, loaded 4 iters ago)
            Row8 r3 = ring[(i + 4) & 7];
            // prefetch input row sy+6 into slot (i)&7 (its old value, row
            // sy-2, was last read 4 iters ago; carries r1/r2 are copies).
            // Tail prefetches (i >= STRIP-4) are never consumed -> DCE'd.
            ring[i & 7] = load_row8(px, sy + 6, t);

            S6 sn = zero;                  // score row sy+1 (OOB -> zeros)
            if (sy + 1 < H) sn = score_row_exact(r1, r2, r3);

            // Shared-column NMS max: bit-identical to the 9-way tree (max is
            // exactly associative/commutative); fuses to v_max3_f32.
            float m3[6];
#pragma unroll
            for (int q = 0; q < 6; ++q)
                m3[q] = fmaxf(fmaxf(sp.s[q], sc_.s[q]), sn.s[q]);

            float4 o;
            float* ov = (float*)&o;
#pragma unroll
            for (int j = 0; j < 4; ++j) {
                float s = sc_.s[j + 1];
                smax = fmaxf(smax, s);
                float m = fmaxf(fmaxf(m3[j], m3[j + 1]), m3[j + 2]);
                ov[j] = (s == m) ? s : 0.0f;
            }
            *(float4*)(po + (size_t)sy * W + (t << 2)) = o;

            r1 = r2; r2 = r3;
            sp = sc_; sc_ = sn;
        }
    }

#pragma unroll
    for (int off = 32; off > 0; off >>= 1)
        smax = fmaxf(smax, __shfl_down(smax, off));
    if ((t & 63) == 0)
        atomicMax(pmax + plane, __float_as_uint(smax));
}

// ---------------- K2: in-place normalize (pure streaming) -------------------
__global__ __launch_bounds__(256) void hess_scale(
    float* __restrict__ out, const unsigned int* __restrict__ pmax)
{
    const int plane = blockIdx.y;
    const float inv = 1.0f / __uint_as_float(pmax[plane]);
    float4* p = (float4*)(out + (size_t)plane * HW);
    const int idx = blockIdx.x * 256 + threadIdx.x;   // 0 .. 65535
#pragma unroll
    for (int k = 0; k < 4; ++k) {
        float4 v = p[idx + (k << 16)];
        v.x *= inv; v.y *= inv; v.z *= inv; v.w *= inv;
        p[idx + (k << 16)] = v;
    }
}

extern "C" void kernel_launch(void* const* d_in, const int* in_sizes, int n_in,
                              void* d_out, int out_size, void* d_ws, size_t ws_size,
                              hipStream_t stream) {
    const float* x = (const float*)d_in[0];
    float* out = (float*)d_out;
    unsigned int* pmax = (unsigned int*)d_ws;
    const int planes = in_sizes[0] / HW;   // 48

    hipMemsetAsync(pmax, 0, planes * sizeof(unsigned int), stream);

    dim3 grid1(H / STRIP, planes);         // 32 x 48 = 1536 blocks
    hess_score_nms<<<grid1, 256, 0, stream>>>(x, out, pmax);

    dim3 grid2(256, planes);               // 256 thr x 4 float4 = 4096 f/blk
    hess_scale<<<grid2, 256, 0, stream>>>(out, pmax);
}